// Round 2
// baseline (422.831 us; speedup 1.0000x reference)
//
#include <hip/hip_runtime.h>

// 4-level 2D Haar DWT (pywt db1), fully fused in ONE kernel. FP32 in / FP32 out
// (per the reference dtypes; R1's NaN proved the input is fp32 — bf16
// reinterpretation of fp32 bytes manufactures NaNs from mantissa bits).
//
// x (64,3,512,512) f32 -> level k: (192, 4, 512/2^k, 512/2^k), concatenated
// flat in d_out. A 64x64 input tile produces exactly the 32/16/8/4 coefficient
// tiles of levels 1..4, so the cA chain lives entirely in LDS (~24 KB/block)
// and never round-trips HBM. Ideal traffic: 201.3 MB in + 267.4 MB out =
// 468.7 MB -> ~74 us at 6.3 TB/s achievable.

#define S0 68   // LDS row strides (non-power-of-2; float4-aligned at the
#define S1 36   // even-row, col%4 addresses actually used)
#define S2 20
#define S3 12

__device__ __forceinline__ void haar2(float a, float b, float c, float d,
                                      float& cA, float& cH, float& cV, float& cD) {
  // a=x[2i,2j] b=x[2i,2j+1] c=x[2i+1,2j] d=x[2i+1,2j+1]
  float s = a + b, t = c + d, u = a - b, v = c - d;
  cA = (s + t) * 0.5f;   // (a+b+c+d)/2
  cH = (s - t) * 0.5f;   // (a+b-c-d)/2
  cV = (u + v) * 0.5f;   // (a-b+c-d)/2
  cD = (u - v) * 0.5f;   // (a-b-c+d)/2
}

// One thread handles a PAIR of adjacent output columns (2*j2, 2*j2+1) of row i:
// reads two float4 rows from LDS, writes float2 per plane.
__device__ __forceinline__ void level_pair(const float* __restrict__ tin, int sin,
                                           float* __restrict__ tout, int sout,
                                           float* __restrict__ gout,
                                           size_t pstride, int gw,
                                           int gy, int gx, int i, int j2) {
  float4 r0 = *(const float4*)&tin[(2 * i) * sin + 4 * j2];       // a0 b0 a1 b1
  float4 r1 = *(const float4*)&tin[(2 * i + 1) * sin + 4 * j2];   // c0 d0 c1 d1
  float a0, h0, v0, d0, a1, h1, v1, d1;
  haar2(r0.x, r0.y, r1.x, r1.y, a0, h0, v0, d0);
  haar2(r0.z, r0.w, r1.z, r1.w, a1, h1, v1, d1);
  if (tout) *(float2*)&tout[i * sout + 2 * j2] = make_float2(a0, a1);
  size_t base = (size_t)gy * gw + gx;
  *(float2*)&gout[base]               = make_float2(a0, a1); // cA
  *(float2*)&gout[base + pstride]     = make_float2(h0, h1); // cH
  *(float2*)&gout[base + 2 * pstride] = make_float2(v0, v1); // cV
  *(float2*)&gout[base + 3 * pstride] = make_float2(d0, d1); // cD
}

__global__ __launch_bounds__(256) void dwt4_kernel(const float* __restrict__ x,
                                                   float* __restrict__ out) {
  __shared__ float t0[64 * S0];  // 17408 B
  __shared__ float t1[32 * S1];  //  4608 B
  __shared__ float t2[16 * S2];  //  1280 B
  __shared__ float t3[8 * S3];   //   384 B   -> 23.7 KB total, 6 blocks/CU

  const int tid = threadIdx.x;
  const int tx  = blockIdx.x & 7;   // 8x8 tiles of 64x64 over the 512x512 image
  const int ty  = blockIdx.x >> 3;
  const int img = blockIdx.y;       // 0..191  (b*3 + ch)

  // ---- stage: 64x64 fp32 tile -> LDS, float4 (16 B) loads ----
  const size_t in_base = (size_t)img * (512 * 512)
                       + (size_t)(ty * 64) * 512 + (size_t)(tx * 64);
#pragma unroll
  for (int k = 0; k < 4; ++k) {
    int chunk = k * 256 + tid;        // 0..1023 = 64 rows x 16 chunks
    int r = chunk >> 4;
    int c = (chunk & 15) * 4;
    float4 u = *(const float4*)(x + in_base + (size_t)r * 512 + c);
    *(float4*)&t0[r * S0 + c] = u;
  }
  __syncthreads();

  // output sections (fp32 element offsets), per-image bases folded in
  float* o1 = out +                   (size_t)img * 4 * 65536; // (192,4,256,256)
  float* o2 = out + (size_t)50331648 + (size_t)img * 4 * 16384; // (192,4,128,128)
  float* o3 = out + (size_t)62914560 + (size_t)img * 4 * 4096;  // (192,4, 64, 64)
  float* o4 = out + (size_t)66060288 + (size_t)img * 4 * 1024;  // (192,4, 32, 32)

  // ---- level 1: 64x64 -> 4 x 32x32 (512 column-pairs, 2 per thread) ----
#pragma unroll
  for (int m = 0; m < 2; ++m) {
    int p = m * 256 + tid;
    int i = p >> 4, j2 = p & 15;
    level_pair(t0, S0, t1, S1, o1, 65536, 256, ty * 32 + i, tx * 32 + 2 * j2, i, j2);
  }
  __syncthreads();

  // ---- level 2: 32x32 -> 4 x 16x16 (128 pairs) ----
  if (tid < 128) {
    int i = tid >> 3, j2 = tid & 7;
    level_pair(t1, S1, t2, S2, o2, 16384, 128, ty * 16 + i, tx * 16 + 2 * j2, i, j2);
  }
  __syncthreads();

  // ---- level 3: 16x16 -> 4 x 8x8 (32 pairs) ----
  if (tid < 32) {
    int i = tid >> 2, j2 = tid & 3;
    level_pair(t2, S2, t3, S3, o3, 4096, 64, ty * 8 + i, tx * 8 + 2 * j2, i, j2);
  }
  __syncthreads();

  // ---- level 4: 8x8 -> 4 x 4x4 (8 pairs) ----
  if (tid < 8) {
    int i = tid >> 1, j2 = tid & 1;
    level_pair(t3, S3, nullptr, 0, o4, 1024, 32, ty * 4 + i, tx * 4 + 2 * j2, i, j2);
  }
}

extern "C" void kernel_launch(void* const* d_in, const int* in_sizes, int n_in,
                              void* d_out, int out_size, void* d_ws, size_t ws_size,
                              hipStream_t stream) {
  const float* x = (const float*)d_in[0];
  float* out = (float*)d_out;
  dim3 grid(64, 192), block(256);
  dwt4_kernel<<<grid, block, 0, stream>>>(x, out);
}